// Round 12
// baseline (601.659 us; speedup 1.0000x reference)
//
#include <hip/hip_runtime.h>

typedef unsigned short u16;
typedef unsigned int u32;
typedef short v8s __attribute__((ext_vector_type(8)));
typedef float v16f __attribute__((ext_vector_type(16)));

#define MFMA(a, b, c) __builtin_amdgcn_mfma_f32_32x32x16_bf16(a, b, c, 0, 0, 0)
#define L2E 1.44269504088896f

union U8 { v8s s; uint4 u4; u32 u[4]; };

__device__ __forceinline__ u16 f2bf(float x) {            // round-nearest-even
    u32 u = __float_as_uint(x);
    return (u16)((u + 0x7FFFu + ((u >> 16) & 1u)) >> 16);
}
__device__ __forceinline__ u32 pk2(float a, float b) {
    return (u32)f2bf(a) | ((u32)f2bf(b) << 16);
}
// RTZ bf16x2 pack in ONE instruction
__device__ __forceinline__ u32 pkz(float e0, float e1) {
    return __builtin_amdgcn_perm(__float_as_uint(e1), __float_as_uint(e0), 0x07060302u);
}

// ======== frag-tiled layouts (u16 units), identical to R8-R11 ========
// qfT/kfT: [b][t32][f][lane][j]   t32 = (q|key)>>5   (4*128*2*512)
// vfT:     [b][ct][tk][lane][j]   ct = ch>>5, tk = key>>4 (4*8*256*512)
// WfT:     [cht][kc][lane][j]     cht = ch>>5 (10)       (160*512)

// ---- prep_w ----
__global__ __launch_bounds__(256) void prep_w_kernel(
    const float* __restrict__ Wq, const float* __restrict__ bq,
    const float* __restrict__ Wk, const float* __restrict__ bk,
    const float* __restrict__ Wv, const float* __restrict__ bv,
    u16* __restrict__ WfT, float* __restrict__ ball)
{
    int tid = blockIdx.x * 256 + threadIdx.x;
    if (tid < 81920) {
        int ch = tid >> 8, c = tid & 255;
        float w;
        if (ch < 32)      w = Wq[ch * 256 + c];
        else if (ch < 64) w = Wk[(ch - 32) * 256 + c] * L2E;
        else              w = Wv[(ch - 64) * 256 + c];
        int tile = (ch >> 5) * 16 + (c >> 4);
        int lane = ((c >> 3) & 1) * 32 + (ch & 31);
        WfT[tile * 512 + lane * 8 + (c & 7)] = f2bf(w);
    } else if (tid < 82240) {
        int i = tid - 81920;
        float bb;
        if (i < 32)      bb = bq[i];
        else if (i < 64) bb = bk[i - 32] * L2E;
        else             bb = bv[i - 64];
        ball[i] = bb;
    }
}

// ---- proj (R10, unchanged): grid 512, 4 waves, 2 blocks/CU ----
__global__ __launch_bounds__(256, 2) void proj_kernel(
    const float* __restrict__ xc, const float* __restrict__ xd,
    const u16* __restrict__ WfT, const float* __restrict__ ball,
    u16* __restrict__ qfT, u16* __restrict__ kfT, u16* __restrict__ vfT)
{
    __shared__ u16 xls[2][32][264];   // [arr][n][c] bf16, 33.8 KB
    int blk = blockIdx.x, b = blk >> 7, n0 = (blk & 127) * 32;
    int t = threadIdx.x, lane = t & 63, wv = t >> 6;
    int hl = lane >> 5, l31 = lane & 31;

#pragma unroll
    for (int p = 0; p < 4; p++) {
        int s = p * 256 + t;
        int arr = s >> 9, c4 = (s >> 3) & 63, n4s = s & 7;
        const float* src = arr ? xd : xc;
        size_t g0 = ((size_t)(b * 256 + c4 * 4)) * 4096 + n0 + n4s * 4;
        float4 r0 = *(const float4*)&src[g0];
        float4 r1 = *(const float4*)&src[g0 + 4096];
        float4 r2 = *(const float4*)&src[g0 + 8192];
        float4 r3 = *(const float4*)&src[g0 + 12288];
        *(uint2*)&xls[arr][n4s * 4 + 0][c4 * 4] = make_uint2(pk2(r0.x, r1.x), pk2(r2.x, r3.x));
        *(uint2*)&xls[arr][n4s * 4 + 1][c4 * 4] = make_uint2(pk2(r0.y, r1.y), pk2(r2.y, r3.y));
        *(uint2*)&xls[arr][n4s * 4 + 2][c4 * 4] = make_uint2(pk2(r0.z, r1.z), pk2(r2.z, r3.z));
        *(uint2*)&xls[arr][n4s * 4 + 3][c4 * 4] = make_uint2(pk2(r0.w, r1.w), pk2(r2.w, r3.w));
    }
    __syncthreads();

    int jobs[3];
    int nj;
    if (wv == 0)      { jobs[0] = 0; jobs[1] = 2; jobs[2] = 0; nj = 2; }
    else if (wv == 1) { jobs[0] = 1; jobs[1] = 3; jobs[2] = 0; nj = 2; }
    else if (wv == 2) { jobs[0] = 4; jobs[1] = 5; jobs[2] = 6; nj = 3; }
    else              { jobs[0] = 7; jobs[1] = 8; jobs[2] = 9; nj = 3; }

    int nt = blk & 127;
    int n = n0 + l31;
    int vl = ((n >> 3) & 1) * 32, tk = n >> 4, j8 = n & 7;

    for (int jj = 0; jj < nj; jj++) {
        int j = jobs[jj];
        int arr = (j != 0);
        const u16* wb = WfT + (size_t)(j * 16) * 512 + lane * 8;
        v16f acc = {};
#pragma unroll
        for (int kc = 0; kc < 16; kc++) {
            U8 bx, a;
            bx.u4 = *(const uint4*)&xls[arr][l31][kc * 16 + hl * 8];
            a.u4  = *(const uint4*)(wb + (size_t)kc * 512);
            acc = MFMA(a.s, bx.s, acc);
        }
        if (j <= 1) {
            u16* dst = j ? kfT : qfT;
#pragma unroll
            for (int i = 0; i < 8; i++) {
                int r = 2 * i;
                int row = (r & 3) + 8 * (r >> 2) + 4 * hl;
                float b0 = ball[j * 32 + row], b1 = ball[j * 32 + row + 1];
                u32 st = pk2(acc[r] + b0, acc[r + 1] + b1);
                size_t off = (((size_t)(b * 128 + nt) * 2 + (row >> 4)) * 512)
                           + (((row >> 3) & 1) * 32 + l31) * 8 + (row & 7);
                *(u32*)&dst[off] = st;
            }
        } else {
            int vi = j - 2;
            u16* vdst = vfT + (((size_t)(b * 8 + vi) * 256 + tk) * 512) + vl * 8 + j8;
#pragma unroll
            for (int r = 0; r < 16; r++) {
                int row = (r & 3) + 8 * (r >> 2) + 4 * hl;
                vdst[row * 8] = f2bf(acc[r] + ball[64 + vi * 32 + row]);
            }
        }
    }
}

// ---- flash R12: TN=32, keys split 4-way ACROSS waves. grid 512, block 512
// ---- = 8 waves (chh:2 x kh:4), 2 blocks/CU -> 4 waves/SIMD (2x R11 TLP).
// ---- Depth-1 register prefetch; two-stage kh-reduction epilogue via LDS.
__global__ __launch_bounds__(512, 4) void flash_kernel(
    const u16* __restrict__ qfT, const u16* __restrict__ kfT,
    const u16* __restrict__ vfT, const float* __restrict__ xccd,
    const float* __restrict__ gptr, float* __restrict__ outp)
{
    __shared__ float red[2][2][4][16][64];   // [chh][slot][ct][reg][lane] 64 KB
    __shared__ float lred[4][32];            // [kh][l31]

    const int t = threadIdx.x, lane = t & 63, wv = t >> 6;
    const int hl = lane >> 5, l31 = lane & 31;
    const int blk = blockIdx.x;
    const int b = (blk & 7) >> 1;                       // XCD-pair pinning
    const int qt = ((blk >> 3) << 1) | (blk & 1);       // 0..127
    const int n0 = qt * 32;
    const int kh = wv & 3, chh = wv >> 2;
    const int chbase = chh * 128;

    U8 qf0, qf1;
    {
        const u16* qp = qfT + ((size_t)(b * 128 + qt) * 2) * 512 + lane * 8;
        qf0.u4 = *(const uint4*)qp;
        qf1.u4 = *(const uint4*)(qp + 512);
    }
    U8 ones;
#pragma unroll
    for (int i = 0; i < 8; i++) ones.s[i] = (short)0x3F80;

    v16f acc[4] = {};
    v16f lac = {};

    const u16* kbase = kfT + ((size_t)b * 128 * 2) * 512 + lane * 8;
    const u16* vbase = vfT + ((size_t)(b * 8 + chh * 4) * 256) * 512 + lane * 8;

    U8 kA[2], kB[2], vA[4][2], vB[4][2];

    // iter i handles key-tile kt = i*4 + kh (32 keys); 32 iters cover 4096 keys
    auto load_frags = [&](int i, U8 (&kf)[2], U8 (&vf)[4][2]) {
        const int kt = i * 4 + kh;
        kf[0].u4 = *(const uint4*)(kbase + (size_t)(kt * 2) * 512);
        kf[1].u4 = *(const uint4*)(kbase + (size_t)(kt * 2 + 1) * 512);
        const int tk = kt * 2;
#pragma unroll
        for (int ct = 0; ct < 4; ct++) {
            const u16* vp = vbase + ((size_t)(ct * 256 + tk)) * 512;
            vf[ct][0].u4 = *(const uint4*)vp;
            vf[ct][1].u4 = *(const uint4*)(vp + 512);
        }
    };

    load_frags(0, kA, vA);

    auto step = [&](int it, U8 (&kf)[2], U8 (&vf)[4][2], U8 (&kn)[2], U8 (&vn)[4][2]) {
        if (it + 1 < 32) load_frags(it + 1, kn, vn);   // depth-1 prefetch
        v16f E = {};
        E = MFMA(kf[0].s, qf0.s, E);
        E = MFMA(kf[1].s, qf1.s, E);
        u32 pkv[8];
#pragma unroll
        for (int j = 0; j < 8; j++)
            pkv[j] = pkz(exp2f(E[2 * j]), exp2f(E[2 * j + 1]));
#pragma unroll
        for (int kc = 0; kc < 2; kc++) {
            const int pb = kc * 4;
            u32 p01 = pkv[pb], p23 = pkv[pb + 1];
            u32 p45 = pkv[pb + 2], p67 = pkv[pb + 3];
            u32 s0 = hl ? p01 : p45;
            u32 s1 = hl ? p23 : p67;
            u32 r0 = (u32)__shfl_xor((int)s0, 32, 64);
            u32 r1 = (u32)__shfl_xor((int)s1, 32, 64);
            U8 B;
            B.u[0] = hl ? r0 : p01;
            B.u[1] = hl ? r1 : p23;
            B.u[2] = hl ? p45 : r0;
            B.u[3] = hl ? p67 : r1;
            if (chh == 0) lac = MFMA(ones.s, B.s, lac);   // one l per kh
#pragma unroll
            for (int ct = 0; ct < 4; ct++)
                acc[ct] = MFMA(vf[ct][kc].s, B.s, acc[ct]);
        }
    };
#pragma unroll 1
    for (int it = 0; it < 32; it += 2) {
        step(it, kA, vA, kB, vB);
        step(it + 1, kB, vB, kA, vA);
    }
    // ---- epilogue: two-stage kh reduction ----
    if (chh == 0 && lane < 32) lred[kh][l31] = lac[0];
    if (kh == 1 || kh == 3) {
        const int slot = kh >> 1;
#pragma unroll
        for (int ct = 0; ct < 4; ct++)
#pragma unroll
            for (int r = 0; r < 16; r++)
                red[chh][slot][ct][r][lane] = acc[ct][r];
    }
    __syncthreads();
    if (kh == 0 || kh == 2) {
        const int slot = kh >> 1;
#pragma unroll
        for (int ct = 0; ct < 4; ct++)
#pragma unroll
            for (int r = 0; r < 16; r++)
                acc[ct][r] += red[chh][slot][ct][r][lane];
        if (kh == 2) {
#pragma unroll
            for (int ct = 0; ct < 4; ct++)
#pragma unroll
                for (int r = 0; r < 16; r++)
                    red[chh][1][ct][r][lane] = acc[ct][r];
        }
    }
    __syncthreads();
    if (kh == 0) {
        const float g = gptr[0];
        const float sc = g / (lred[0][l31] + lred[1][l31] + lred[2][l31] + lred[3][l31]);
#pragma unroll
        for (int ct = 0; ct < 4; ct++)
#pragma unroll
            for (int r = 0; r < 16; r++) {
                float v = acc[ct][r] + red[chh][1][ct][r][lane];
                int ch = chbase + ct * 32 + (r & 3) + 8 * (r >> 2) + 4 * hl;
                size_t ga = ((size_t)(b * 256 + ch)) * 4096 + n0 + l31;
                outp[ga] = v * sc + xccd[ga];
            }
    }
}

extern "C" void kernel_launch(void* const* d_in, const int* in_sizes, int n_in,
                              void* d_out, int out_size, void* d_ws, size_t ws_size,
                              hipStream_t stream)
{
    const float* xc    = (const float*)d_in[0];
    const float* xd    = (const float*)d_in[1];
    const float* Wq    = (const float*)d_in[2];
    const float* bq    = (const float*)d_in[3];
    const float* Wk    = (const float*)d_in[4];
    const float* bk    = (const float*)d_in[5];
    const float* Wv    = (const float*)d_in[6];
    const float* bv    = (const float*)d_in[7];
    const float* gamma = (const float*)d_in[8];
    float* out = (float*)d_out;

    // ws (u16): qfT 512K | kfT 512K | vfT 4M | WfT 80K | ball
    u16* qfT  = (u16*)d_ws;
    u16* kfT  = qfT + (size_t)524288;
    u16* vfT  = kfT + (size_t)524288;
    u16* WfT  = vfT + (size_t)4194304;
    float* bl = (float*)(WfT + 81920);

    prep_w_kernel<<<322, 256, 0, stream>>>(Wq, bq, Wk, bk, Wv, bv, WfT, bl);
    proj_kernel<<<512, 256, 0, stream>>>(xc, xd, WfT, bl, qfT, kfT, vfT);
    flash_kernel<<<512, 512, 0, stream>>>(qfT, kfT, vfT, xc, gamma, out);
}

// Round 13
// 171.729 us; speedup vs baseline: 3.5035x; 3.5035x over previous
//
#include <hip/hip_runtime.h>

typedef unsigned short u16;
typedef unsigned int u32;
typedef short v8s __attribute__((ext_vector_type(8)));
typedef float v16f __attribute__((ext_vector_type(16)));

#define MFMA(a, b, c) __builtin_amdgcn_mfma_f32_32x32x16_bf16(a, b, c, 0, 0, 0)
#define L2E 1.44269504088896f

union U8 { v8s s; uint4 u4; u32 u[4]; };

__device__ __forceinline__ u16 f2bf(float x) {            // round-nearest-even
    u32 u = __float_as_uint(x);
    return (u16)((u + 0x7FFFu + ((u >> 16) & 1u)) >> 16);
}
__device__ __forceinline__ u32 pk2(float a, float b) {
    return (u32)f2bf(a) | ((u32)f2bf(b) << 16);
}
// RTZ bf16x2 pack in ONE instruction
__device__ __forceinline__ u32 pkz(float e0, float e1) {
    return __builtin_amdgcn_perm(__float_as_uint(e1), __float_as_uint(e0), 0x07060302u);
}

// ======== frag-tiled layouts (u16 units), identical to R8-R12 ========
// qfT/kfT: [b][t32][f][lane][j]   t32 = (q|key)>>5   (4*128*2*512)
// vfT:     [b][ct][tk][lane][j]   ct = ch>>5, tk = key>>4 (4*8*256*512)
// WfT:     [cht][kc][lane][j]     cht = ch>>5 (10)       (160*512)

// ---- prep_w ----
__global__ __launch_bounds__(256) void prep_w_kernel(
    const float* __restrict__ Wq, const float* __restrict__ bq,
    const float* __restrict__ Wk, const float* __restrict__ bk,
    const float* __restrict__ Wv, const float* __restrict__ bv,
    u16* __restrict__ WfT, float* __restrict__ ball)
{
    int tid = blockIdx.x * 256 + threadIdx.x;
    if (tid < 81920) {
        int ch = tid >> 8, c = tid & 255;
        float w;
        if (ch < 32)      w = Wq[ch * 256 + c];
        else if (ch < 64) w = Wk[(ch - 32) * 256 + c] * L2E;
        else              w = Wv[(ch - 64) * 256 + c];
        int tile = (ch >> 5) * 16 + (c >> 4);
        int lane = ((c >> 3) & 1) * 32 + (ch & 31);
        WfT[tile * 512 + lane * 8 + (c & 7)] = f2bf(w);
    } else if (tid < 82240) {
        int i = tid - 81920;
        float bb;
        if (i < 32)      bb = bq[i];
        else if (i < 64) bb = bk[i - 32] * L2E;
        else             bb = bv[i - 64];
        ball[i] = bb;
    }
}

// ---- proj (R10, unchanged): grid 512, 4 waves, 2 blocks/CU ----
__global__ __launch_bounds__(256, 2) void proj_kernel(
    const float* __restrict__ xc, const float* __restrict__ xd,
    const u16* __restrict__ WfT, const float* __restrict__ ball,
    u16* __restrict__ qfT, u16* __restrict__ kfT, u16* __restrict__ vfT)
{
    __shared__ u16 xls[2][32][264];   // [arr][n][c] bf16, 33.8 KB
    int blk = blockIdx.x, b = blk >> 7, n0 = (blk & 127) * 32;
    int t = threadIdx.x, lane = t & 63, wv = t >> 6;
    int hl = lane >> 5, l31 = lane & 31;

#pragma unroll
    for (int p = 0; p < 4; p++) {
        int s = p * 256 + t;
        int arr = s >> 9, c4 = (s >> 3) & 63, n4s = s & 7;
        const float* src = arr ? xd : xc;
        size_t g0 = ((size_t)(b * 256 + c4 * 4)) * 4096 + n0 + n4s * 4;
        float4 r0 = *(const float4*)&src[g0];
        float4 r1 = *(const float4*)&src[g0 + 4096];
        float4 r2 = *(const float4*)&src[g0 + 8192];
        float4 r3 = *(const float4*)&src[g0 + 12288];
        *(uint2*)&xls[arr][n4s * 4 + 0][c4 * 4] = make_uint2(pk2(r0.x, r1.x), pk2(r2.x, r3.x));
        *(uint2*)&xls[arr][n4s * 4 + 1][c4 * 4] = make_uint2(pk2(r0.y, r1.y), pk2(r2.y, r3.y));
        *(uint2*)&xls[arr][n4s * 4 + 2][c4 * 4] = make_uint2(pk2(r0.z, r1.z), pk2(r2.z, r3.z));
        *(uint2*)&xls[arr][n4s * 4 + 3][c4 * 4] = make_uint2(pk2(r0.w, r1.w), pk2(r2.w, r3.w));
    }
    __syncthreads();

    int jobs[3];
    int nj;
    if (wv == 0)      { jobs[0] = 0; jobs[1] = 2; jobs[2] = 0; nj = 2; }
    else if (wv == 1) { jobs[0] = 1; jobs[1] = 3; jobs[2] = 0; nj = 2; }
    else if (wv == 2) { jobs[0] = 4; jobs[1] = 5; jobs[2] = 6; nj = 3; }
    else              { jobs[0] = 7; jobs[1] = 8; jobs[2] = 9; nj = 3; }

    int nt = blk & 127;
    int n = n0 + l31;
    int vl = ((n >> 3) & 1) * 32, tk = n >> 4, j8 = n & 7;

    for (int jj = 0; jj < nj; jj++) {
        int j = jobs[jj];
        int arr = (j != 0);
        const u16* wb = WfT + (size_t)(j * 16) * 512 + lane * 8;
        v16f acc = {};
#pragma unroll
        for (int kc = 0; kc < 16; kc++) {
            U8 bx, a;
            bx.u4 = *(const uint4*)&xls[arr][l31][kc * 16 + hl * 8];
            a.u4  = *(const uint4*)(wb + (size_t)kc * 512);
            acc = MFMA(a.s, bx.s, acc);
        }
        if (j <= 1) {
            u16* dst = j ? kfT : qfT;
#pragma unroll
            for (int i = 0; i < 8; i++) {
                int r = 2 * i;
                int row = (r & 3) + 8 * (r >> 2) + 4 * hl;
                float b0 = ball[j * 32 + row], b1 = ball[j * 32 + row + 1];
                u32 st = pk2(acc[r] + b0, acc[r + 1] + b1);
                size_t off = (((size_t)(b * 128 + nt) * 2 + (row >> 4)) * 512)
                           + (((row >> 3) & 1) * 32 + l31) * 8 + (row & 7);
                *(u32*)&dst[off] = st;
            }
        } else {
            int vi = j - 2;
            u16* vdst = vfT + (((size_t)(b * 8 + vi) * 256 + tk) * 512) + vl * 8 + j8;
#pragma unroll
            for (int r = 0; r < 16; r++) {
                int row = (r & 3) + 8 * (r >> 2) + 4 * hl;
                vdst[row * 8] = f2bf(acc[r] + ball[64 + vi * 32 + row]);
            }
        }
    }
}

// ---- flash R13: R12 key-split structure, launch_bounds reverted to (512,2)
// ---- (R12's (512,4) forced VGPR 124->64 => scratch spill, 880MB fetch).
// ---- LDS 64.5KB admits 2 blocks/CU; VGPR ~110 <= 128 keeps 16 waves/CU.
__global__ __launch_bounds__(512, 2) void flash_kernel(
    const u16* __restrict__ qfT, const u16* __restrict__ kfT,
    const u16* __restrict__ vfT, const float* __restrict__ xccd,
    const float* __restrict__ gptr, float* __restrict__ outp)
{
    __shared__ float red[2][2][4][16][64];   // [chh][slot][ct][reg][lane] 64 KB
    __shared__ float lred[4][32];            // [kh][l31]

    const int t = threadIdx.x, lane = t & 63, wv = t >> 6;
    const int hl = lane >> 5, l31 = lane & 31;
    const int blk = blockIdx.x;
    const int b = (blk & 7) >> 1;                       // XCD-pair pinning
    const int qt = ((blk >> 3) << 1) | (blk & 1);       // 0..127
    const int n0 = qt * 32;
    const int kh = wv & 3, chh = wv >> 2;
    const int chbase = chh * 128;

    U8 qf0, qf1;
    {
        const u16* qp = qfT + ((size_t)(b * 128 + qt) * 2) * 512 + lane * 8;
        qf0.u4 = *(const uint4*)qp;
        qf1.u4 = *(const uint4*)(qp + 512);
    }
    U8 ones;
#pragma unroll
    for (int i = 0; i < 8; i++) ones.s[i] = (short)0x3F80;

    v16f acc[4] = {};
    v16f lac = {};

    const u16* kbase = kfT + ((size_t)b * 128 * 2) * 512 + lane * 8;
    const u16* vbase = vfT + ((size_t)(b * 8 + chh * 4) * 256) * 512 + lane * 8;

    U8 kA[2], kB[2], vA[4][2], vB[4][2];

    // iter i handles key-tile kt = i*4 + kh (32 keys); 32 iters cover 4096 keys
    auto load_frags = [&](int i, U8 (&kf)[2], U8 (&vf)[4][2]) {
        const int kt = i * 4 + kh;
        kf[0].u4 = *(const uint4*)(kbase + (size_t)(kt * 2) * 512);
        kf[1].u4 = *(const uint4*)(kbase + (size_t)(kt * 2 + 1) * 512);
        const int tk = kt * 2;
#pragma unroll
        for (int ct = 0; ct < 4; ct++) {
            const u16* vp = vbase + ((size_t)(ct * 256 + tk)) * 512;
            vf[ct][0].u4 = *(const uint4*)vp;
            vf[ct][1].u4 = *(const uint4*)(vp + 512);
        }
    };

    load_frags(0, kA, vA);

    auto step = [&](int it, U8 (&kf)[2], U8 (&vf)[4][2], U8 (&kn)[2], U8 (&vn)[4][2]) {
        if (it + 1 < 32) load_frags(it + 1, kn, vn);   // depth-1 prefetch
        v16f E = {};
        E = MFMA(kf[0].s, qf0.s, E);
        E = MFMA(kf[1].s, qf1.s, E);
        u32 pkv[8];
#pragma unroll
        for (int j = 0; j < 8; j++)
            pkv[j] = pkz(exp2f(E[2 * j]), exp2f(E[2 * j + 1]));
#pragma unroll
        for (int kc = 0; kc < 2; kc++) {
            const int pb = kc * 4;
            u32 p01 = pkv[pb], p23 = pkv[pb + 1];
            u32 p45 = pkv[pb + 2], p67 = pkv[pb + 3];
            u32 s0 = hl ? p01 : p45;
            u32 s1 = hl ? p23 : p67;
            u32 r0 = (u32)__shfl_xor((int)s0, 32, 64);
            u32 r1 = (u32)__shfl_xor((int)s1, 32, 64);
            U8 B;
            B.u[0] = hl ? r0 : p01;
            B.u[1] = hl ? r1 : p23;
            B.u[2] = hl ? p45 : r0;
            B.u[3] = hl ? p67 : r1;
            if (chh == 0) lac = MFMA(ones.s, B.s, lac);   // one l per kh
#pragma unroll
            for (int ct = 0; ct < 4; ct++)
                acc[ct] = MFMA(vf[ct][kc].s, B.s, acc[ct]);
        }
    };
#pragma unroll 1
    for (int it = 0; it < 32; it += 2) {
        step(it, kA, vA, kB, vB);
        step(it + 1, kB, vB, kA, vA);
    }
    // ---- epilogue: two-stage kh reduction ----
    if (chh == 0 && lane < 32) lred[kh][l31] = lac[0];
    if (kh == 1 || kh == 3) {
        const int slot = kh >> 1;
#pragma unroll
        for (int ct = 0; ct < 4; ct++)
#pragma unroll
            for (int r = 0; r < 16; r++)
                red[chh][slot][ct][r][lane] = acc[ct][r];
    }
    __syncthreads();
    if (kh == 0 || kh == 2) {
        const int slot = kh >> 1;
#pragma unroll
        for (int ct = 0; ct < 4; ct++)
#pragma unroll
            for (int r = 0; r < 16; r++)
                acc[ct][r] += red[chh][slot][ct][r][lane];
        if (kh == 2) {
#pragma unroll
            for (int ct = 0; ct < 4; ct++)
#pragma unroll
                for (int r = 0; r < 16; r++)
                    red[chh][1][ct][r][lane] = acc[ct][r];
        }
    }
    __syncthreads();
    if (kh == 0) {
        const float g = gptr[0];
        const float sc = g / (lred[0][l31] + lred[1][l31] + lred[2][l31] + lred[3][l31]);
#pragma unroll
        for (int ct = 0; ct < 4; ct++)
#pragma unroll
            for (int r = 0; r < 16; r++) {
                float v = acc[ct][r] + red[chh][1][ct][r][lane];
                int ch = chbase + ct * 32 + (r & 3) + 8 * (r >> 2) + 4 * hl;
                size_t ga = ((size_t)(b * 256 + ch)) * 4096 + n0 + l31;
                outp[ga] = v * sc + xccd[ga];
            }
    }
}

extern "C" void kernel_launch(void* const* d_in, const int* in_sizes, int n_in,
                              void* d_out, int out_size, void* d_ws, size_t ws_size,
                              hipStream_t stream)
{
    const float* xc    = (const float*)d_in[0];
    const float* xd    = (const float*)d_in[1];
    const float* Wq    = (const float*)d_in[2];
    const float* bq    = (const float*)d_in[3];
    const float* Wk    = (const float*)d_in[4];
    const float* bk    = (const float*)d_in[5];
    const float* Wv    = (const float*)d_in[6];
    const float* bv    = (const float*)d_in[7];
    const float* gamma = (const float*)d_in[8];
    float* out = (float*)d_out;

    // ws (u16): qfT 512K | kfT 512K | vfT 4M | WfT 80K | ball
    u16* qfT  = (u16*)d_ws;
    u16* kfT  = qfT + (size_t)524288;
    u16* vfT  = kfT + (size_t)524288;
    u16* WfT  = vfT + (size_t)4194304;
    float* bl = (float*)(WfT + 81920);

    prep_w_kernel<<<322, 256, 0, stream>>>(Wq, bq, Wk, bk, Wv, bv, WfT, bl);
    proj_kernel<<<512, 256, 0, stream>>>(xc, xd, WfT, bl, qfT, kfT, vfT);
    flash_kernel<<<512, 512, 0, stream>>>(qfT, kfT, vfT, xc, gamma, out);
}